// Round 1
// baseline (677.059 us; speedup 1.0000x reference)
//
#include <hip/hip_runtime.h>
#include <math.h>

// Problem constants
#define B_  4
#define C1_ 256
#define C2_ 256
#define H_  64
#define W_  64
#define KK_ 9
#define MAX_OFF_ 6.0f
#define BN_EPS_ 1e-5f

// ws layout (floats):
//   py:   [B][KK][H][W]   = 147456
//   px:   +147456
//   mask: +294912
//   Wt:   +442368  [C1*KK][C2] = 589824
#define WS_PY   0
#define WS_PX   147456
#define WS_MASK 294912
#define WS_WT   442368

// ---------------------------------------------------------------------------
// Kernel A: offset/mask conv (27 out ch, 3x3, pad 1) + transform to py/px/mask
// block = 256 threads = 4 c-groups x 64 w ; grid = B*H
// ---------------------------------------------------------------------------
__global__ __launch_bounds__(256) void om_kernel(
    const float* __restrict__ x, const float* __restrict__ w_om,
    const float* __restrict__ b_om, float* __restrict__ ws) {
  const int bid = blockIdx.x;
  const int b = bid >> 6, h = bid & 63;
  const int tid = threadIdx.x;
  const int cg = tid >> 6, w = tid & 63;

  float acc[27];
#pragma unroll
  for (int i = 0; i < 27; ++i) acc[i] = 0.f;

  const float* xb = x + ((size_t)b * C1_ + cg * 64) * (H_ * W_);

  for (int cc = 0; cc < 64; ++cc) {
    const float* xc = xb + cc * (H_ * W_);
    float xv[9];
#pragma unroll
    for (int dy = 0; dy < 3; ++dy) {
      const int hh = h - 1 + dy;
      const bool vy = ((unsigned)hh < (unsigned)H_);
#pragma unroll
      for (int dx = 0; dx < 3; ++dx) {
        const int ww = w - 1 + dx;
        const bool v = vy && ((unsigned)ww < (unsigned)W_);
        xv[dy * 3 + dx] = v ? xc[hh * W_ + ww] : 0.f;
      }
    }
    const int c = cg * 64 + cc;
#pragma unroll
    for (int oc = 0; oc < 27; ++oc) {
      const float* wo = w_om + ((size_t)oc * C1_ + c) * 9;
#pragma unroll
      for (int t = 0; t < 9; ++t) acc[oc] = fmaf(wo[t], xv[t], acc[oc]);
    }
  }

  // reduce across the 4 c-groups via LDS
  __shared__ float red[3][64][28];
  if (cg > 0) {
#pragma unroll
    for (int oc = 0; oc < 27; ++oc) red[cg - 1][w][oc] = acc[oc];
  }
  __syncthreads();
  if (cg == 0) {
#pragma unroll
    for (int oc = 0; oc < 27; ++oc) {
      acc[oc] += red[0][w][oc] + red[1][w][oc] + red[2][w][oc];
      acc[oc] += b_om[oc];
    }
    float* py = ws + WS_PY;
    float* px = ws + WS_PX;
    float* pm = ws + WS_MASK;
#pragma unroll
    for (int kk = 0; kk < 9; ++kk) {
      float dy = fminf(fmaxf(acc[2 * kk], -MAX_OFF_), MAX_OFF_);
      float dx = fminf(fmaxf(acc[2 * kk + 1], -MAX_OFF_), MAX_OFF_);
      float m = 1.f / (1.f + expf(-acc[18 + kk]));
      const int idx = ((b * KK_ + kk) * H_ + h) * W_ + w;
      py[idx] = (float)(h - 1 + kk / 3) + dy;
      px[idx] = (float)(w - 1 + kk % 3) + dx;
      pm[idx] = m;
    }
  }
}

// ---------------------------------------------------------------------------
// Kernel C: transpose w_dcn [C2][C1*KK] -> Wt [C1*KK][C2]
// ---------------------------------------------------------------------------
__global__ __launch_bounds__(256) void wt_kernel(const float* __restrict__ w_dcn,
                                                 float* __restrict__ ws) {
  const int t = blockIdx.x * 256 + threadIdx.x;  // t < 2304*256
  const int o = t & 255;
  const int ck = t >> 8;
  float* Wt = ws + WS_WT;
  Wt[t] = w_dcn[(size_t)o * (C1_ * KK_) + ck];
}

// ---------------------------------------------------------------------------
// Kernel B: fused deformable conv + BN + SiLU
// block: 128 o x 64 w (one output row), 256 threads, micro-tile 8o x 4w
// grid = B*H*2 ; bid: oh = bit0, h = bits[1..6], b = bits[7..]
// ---------------------------------------------------------------------------
__global__ __launch_bounds__(256) void dcn_kernel(
    const float* __restrict__ x, const float* __restrict__ ws,
    const float* __restrict__ bn_gamma, const float* __restrict__ bn_beta,
    const float* __restrict__ bn_mean, const float* __restrict__ bn_var,
    float* __restrict__ out) {
  const int bid = blockIdx.x;
  const int oh = bid & 1;
  const int h = (bid >> 1) & 63;
  const int b = bid >> 7;
  const int tid = threadIdx.x;

  __shared__ int sidx[576][4];
  __shared__ float swgt[576][4];
  __shared__ float scol[576];      // [k][w]
  __shared__ float swt[9 * 128];   // [k][o_local]

  const float* py = ws + WS_PY;
  const float* px = ws + WS_PX;
  const float* pm = ws + WS_MASK;
  const float* Wt = ws + WS_WT;

  // ---- stage sampling metadata (per (k,w), shared over all c and o) ----
  for (int t = tid; t < 576; t += 256) {
    const int k = t >> 6, w = t & 63;
    const int base = ((b * KK_ + k) * H_ + h) * W_ + w;
    const float yy = py[base];
    const float xx = px[base];
    const float m = pm[base];
    const float y0f = floorf(yy), x0f = floorf(xx);
    const float ly = yy - y0f, lx = xx - x0f;
    const int y0 = (int)y0f, x0 = (int)x0f;
    const int y1 = y0 + 1, x1 = x0 + 1;
    const bool vy0 = ((unsigned)y0 < (unsigned)H_);
    const bool vy1 = ((unsigned)y1 < (unsigned)H_);
    const bool vx0 = ((unsigned)x0 < (unsigned)W_);
    const bool vx1 = ((unsigned)x1 < (unsigned)W_);
    const int y0c = min(max(y0, 0), H_ - 1), y1c = min(max(y1, 0), H_ - 1);
    const int x0c = min(max(x0, 0), W_ - 1), x1c = min(max(x1, 0), W_ - 1);
    sidx[t][0] = y0c * W_ + x0c;
    sidx[t][1] = y0c * W_ + x1c;
    sidx[t][2] = y1c * W_ + x0c;
    sidx[t][3] = y1c * W_ + x1c;
    swgt[t][0] = (1.f - ly) * (1.f - lx) * ((vy0 && vx0) ? m : 0.f);
    swgt[t][1] = (1.f - ly) * lx * ((vy0 && vx1) ? m : 0.f);
    swgt[t][2] = ly * (1.f - lx) * ((vy1 && vx0) ? m : 0.f);
    swgt[t][3] = ly * lx * ((vy1 && vx1) ? m : 0.f);
  }

  float acc[8][4];
#pragma unroll
  for (int i = 0; i < 8; ++i)
#pragma unroll
    for (int j = 0; j < 4; ++j) acc[i][j] = 0.f;

  const float* xb = x + (size_t)b * C1_ * (H_ * W_);
  const int og = tid & 15;   // o-group: o_local = og*8 .. og*8+7
  const int wg = tid >> 4;   // w-group: w = wg*4 .. wg*4+3

  __syncthreads();  // meta ready

  for (int c = 0; c < C1_; ++c) {
    // compute col samples + load Wt chunk into registers (no LDS writes yet)
    const float* xc = xb + c * (H_ * W_);
    float colv[3];
    int nr = 0;
#pragma unroll
    for (int r = 0; r < 3; ++r) {
      const int t = tid + r * 256;
      if (t < 576) {
        const int4 id = *(const int4*)sidx[t];
        const float4 wv = *(const float4*)swgt[t];
        colv[r] = wv.x * xc[id.x] + wv.y * xc[id.y] + wv.z * xc[id.z] +
                  wv.w * xc[id.w];
        nr = r + 1;
      }
    }
    float wtv[5];
    const float* wsrc = Wt + (size_t)c * KK_ * C2_ + oh * 128;
#pragma unroll
    for (int r = 0; r < 5; ++r) {
      const int t = tid + r * 256;
      if (t < 1152) {
        const int k = t >> 7, ol = t & 127;
        wtv[r] = wsrc[k * C2_ + ol];
      }
    }

    __syncthreads();  // previous iteration's reads of scol/swt done

#pragma unroll
    for (int r = 0; r < 3; ++r) {
      const int t = tid + r * 256;
      if (t < 576) scol[t] = colv[r];
    }
#pragma unroll
    for (int r = 0; r < 5; ++r) {
      const int t = tid + r * 256;
      if (t < 1152) swt[t] = wtv[r];
    }
    (void)nr;

    __syncthreads();  // staged

    // rank-1 updates: acc[i][j] += wt[k][og*8+i] * col[k][wg*4+j]
#pragma unroll
    for (int k = 0; k < 9; ++k) {
      const float4 cv = *(const float4*)&scol[k * 64 + wg * 4];
      const float4 wv0 = *(const float4*)&swt[k * 128 + og * 8];
      const float4 wv1 = *(const float4*)&swt[k * 128 + og * 8 + 4];
      const float wvv[8] = {wv0.x, wv0.y, wv0.z, wv0.w,
                            wv1.x, wv1.y, wv1.z, wv1.w};
      const float cvv[4] = {cv.x, cv.y, cv.z, cv.w};
#pragma unroll
      for (int i = 0; i < 8; ++i)
#pragma unroll
        for (int j = 0; j < 4; ++j)
          acc[i][j] = fmaf(wvv[i], cvv[j], acc[i][j]);
    }
  }

  // ---- epilogue: BN + SiLU + store ----
  const int o0 = oh * 128 + og * 8;
#pragma unroll
  for (int i = 0; i < 8; ++i) {
    const int o = o0 + i;
    const float inv = bn_gamma[o] * rsqrtf(bn_var[o] + BN_EPS_);
    const float bb = bn_beta[o] - bn_mean[o] * inv;
    float4 v;
    float* vv = (float*)&v;
#pragma unroll
    for (int j = 0; j < 4; ++j) {
      float t = acc[i][j] * inv + bb;
      vv[j] = t / (1.f + expf(-t));
    }
    *(float4*)&out[(((size_t)b * C2_ + o) * H_ + h) * W_ + wg * 4] = v;
  }
}

// ---------------------------------------------------------------------------
extern "C" void kernel_launch(void* const* d_in, const int* in_sizes, int n_in,
                              void* d_out, int out_size, void* d_ws,
                              size_t ws_size, hipStream_t stream) {
  const float* x = (const float*)d_in[0];
  const float* w_om = (const float*)d_in[1];
  const float* b_om = (const float*)d_in[2];
  const float* w_dcn = (const float*)d_in[3];
  const float* bn_gamma = (const float*)d_in[4];
  const float* bn_beta = (const float*)d_in[5];
  const float* bn_mean = (const float*)d_in[6];
  const float* bn_var = (const float*)d_in[7];
  float* out = (float*)d_out;
  float* ws = (float*)d_ws;

  // Kernel A: offset/mask conv -> py/px/mask in ws
  om_kernel<<<B_ * H_, 256, 0, stream>>>(x, w_om, b_om, ws);
  // Kernel C: weight transpose -> Wt in ws
  wt_kernel<<<(C1_ * KK_ * C2_) / 256, 256, 0, stream>>>(w_dcn, ws);
  // Kernel B: fused DCN + BN + SiLU
  dcn_kernel<<<B_ * H_ * 2, 256, 0, stream>>>(x, ws, bn_gamma, bn_beta,
                                              bn_mean, bn_var, out);
}

// Round 2
// 334.037 us; speedup vs baseline: 2.0269x; 2.0269x over previous
//
#include <hip/hip_runtime.h>
#include <math.h>

#define B_  4
#define C1_ 256
#define C2_ 256
#define H_  64
#define W_  64
#define HW_ 4096
#define KK_ 9

// ws byte offsets
#define WA_OFF    0u            // bf16 Wa[72][4][256][8]            (1,179,648 B)
#define MIDX_OFF  1179648u      // int4  midx[B][9][4096]            (2,359,296 B)
#define MWGT_OFF  3538944u      // float4 mwgt[B][9][4096]           (2,359,296 B)
#define PART_OFF  5898240u      // float part[4][B][27][4096]        (7,077,888 B)
#define BN_OFF    12976128u     // float inv[256]; bb[256]           (2,048 B)

typedef short bf16x8 __attribute__((ext_vector_type(8)));
typedef float f32x4 __attribute__((ext_vector_type(4)));

__device__ __forceinline__ unsigned f2bfu(float f) {
  unsigned u = __builtin_bit_cast(unsigned, f);
  return (u + 0x7FFFu + ((u >> 16) & 1u)) >> 16;
}

__device__ __forceinline__ void gload_lds16(const void* g, void* l) {
  __builtin_amdgcn_global_load_lds(
      (const __attribute__((address_space(1))) unsigned*)g,
      (__attribute__((address_space(3))) unsigned*)l, 16, 0, 0);
}

// ---------------------------------------------------------------------------
// om_part: offset/mask conv partials. grid = B*H*4 (cg = 64-channel group),
// block = 256 thr = 4 sub(16c) x 64 w. part[cg][b][27][4096] += in ws.
// ---------------------------------------------------------------------------
__global__ __launch_bounds__(256) void om_part(const float* __restrict__ x,
                                               const float* __restrict__ w_om,
                                               char* __restrict__ wsb) {
  const int bid = blockIdx.x;
  const int cg = bid & 3, h = (bid >> 2) & 63, b = bid >> 8;
  const int tid = threadIdx.x;
  const int sub = tid >> 6, w = tid & 63;

  float acc[27];
#pragma unroll
  for (int i = 0; i < 27; ++i) acc[i] = 0.f;

  const int cbase = cg * 64 + sub * 16;
  const float* xp = x + ((size_t)(b * C1_ + cbase)) * HW_;

  for (int cc = 0; cc < 16; ++cc) {
    float xv[9];
#pragma unroll
    for (int dy = 0; dy < 3; ++dy) {
      const int hh = h - 1 + dy;
      const bool vy = ((unsigned)hh < (unsigned)H_);
#pragma unroll
      for (int dx = 0; dx < 3; ++dx) {
        const int ww = w - 1 + dx;
        xv[dy * 3 + dx] =
            (vy && ((unsigned)ww < (unsigned)W_)) ? xp[hh * W_ + ww] : 0.f;
      }
    }
    const int c = cbase + cc;
#pragma unroll
    for (int oc = 0; oc < 27; ++oc) {
      const float* wo = w_om + ((size_t)oc * C1_ + c) * 9;
#pragma unroll
      for (int t = 0; t < 9; ++t) acc[oc] = fmaf(wo[t], xv[t], acc[oc]);
    }
    xp += HW_;
  }

  __shared__ float red[3][64][27];
  if (sub) {
#pragma unroll
    for (int oc = 0; oc < 27; ++oc) red[sub - 1][w][oc] = acc[oc];
  }
  __syncthreads();
  if (!sub) {
    float* part = (float*)(wsb + PART_OFF);
#pragma unroll
    for (int oc = 0; oc < 27; ++oc) {
      float v = acc[oc] + red[0][w][oc] + red[1][w][oc] + red[2][w][oc];
      part[(((size_t)cg * B_ + b) * 27 + oc) * HW_ + h * W_ + w] = v;
    }
  }
}

// ---------------------------------------------------------------------------
// om_final: reduce partials + bias -> clamp/sigmoid -> bilinear meta
// (corner idx int4, mask-premultiplied weights float4). Also BN prep (blk 0).
// grid = 64 x 256 (one thread per (b,p)).
// ---------------------------------------------------------------------------
__global__ __launch_bounds__(256) void om_final(
    const float* __restrict__ b_om, const float* __restrict__ bn_gamma,
    const float* __restrict__ bn_beta, const float* __restrict__ bn_mean,
    const float* __restrict__ bn_var, char* __restrict__ wsb) {
  if (blockIdx.x == 0) {
    const int o = threadIdx.x;
    float inv = bn_gamma[o] * rsqrtf(bn_var[o] + 1e-5f);
    ((float*)(wsb + BN_OFF))[o] = inv;
    ((float*)(wsb + BN_OFF))[256 + o] = bn_beta[o] - bn_mean[o] * inv;
  }
  const int t = blockIdx.x * 256 + threadIdx.x;
  const int b = t >> 12, p = t & 4095;
  const int h = p >> 6, w = p & 63;

  const float* part = (const float*)(wsb + PART_OFF);
  float acc[27];
#pragma unroll
  for (int oc = 0; oc < 27; ++oc) acc[oc] = b_om[oc];
  for (int cg = 0; cg < 4; ++cg)
#pragma unroll
    for (int oc = 0; oc < 27; ++oc)
      acc[oc] += part[(((size_t)cg * B_ + b) * 27 + oc) * HW_ + p];

  int4* midx = (int4*)(wsb + MIDX_OFF);
  float4* mwgt = (float4*)(wsb + MWGT_OFF);
#pragma unroll
  for (int k = 0; k < 9; ++k) {
    float dy = fminf(fmaxf(acc[2 * k], -6.f), 6.f);
    float dx = fminf(fmaxf(acc[2 * k + 1], -6.f), 6.f);
    float m = 1.f / (1.f + expf(-acc[18 + k]));
    float py = (float)(h - 1 + k / 3) + dy;
    float px = (float)(w - 1 + k % 3) + dx;
    float y0f = floorf(py), x0f = floorf(px);
    float ly = py - y0f, lx = px - x0f;
    int y0 = (int)y0f, x0 = (int)x0f;
    int y1 = y0 + 1, x1 = x0 + 1;
    const bool vy0 = ((unsigned)y0 < (unsigned)H_);
    const bool vy1 = ((unsigned)y1 < (unsigned)H_);
    const bool vx0 = ((unsigned)x0 < (unsigned)W_);
    const bool vx1 = ((unsigned)x1 < (unsigned)W_);
    int y0c = min(max(y0, 0), H_ - 1), y1c = min(max(y1, 0), H_ - 1);
    int x0c = min(max(x0, 0), W_ - 1), x1c = min(max(x1, 0), W_ - 1);
    const size_t e = ((size_t)b * KK_ + k) * HW_ + p;
    midx[e] = make_int4(y0c * W_ + x0c, y0c * W_ + x1c, y1c * W_ + x0c,
                        y1c * W_ + x1c);
    mwgt[e] = make_float4((1.f - ly) * (1.f - lx) * ((vy0 && vx0) ? m : 0.f),
                          (1.f - ly) * lx * ((vy0 && vx1) ? m : 0.f),
                          ly * (1.f - lx) * ((vy1 && vx0) ? m : 0.f),
                          ly * lx * ((vy1 && vx1) ? m : 0.f));
  }
}

// ---------------------------------------------------------------------------
// wt_perm: w_dcn [C2][C1][9] -> Wa bf16 [72 kt][4 kg][256 o][8 j],
// where ck = kt*32 + kg*8 + j = k*256 + c  (K reordered k-major).
// ---------------------------------------------------------------------------
__global__ __launch_bounds__(256) void wt_perm(const float* __restrict__ w_dcn,
                                               char* __restrict__ wsb) {
  const unsigned e = blockIdx.x * 256 + threadIdx.x;  // < 589824
  const unsigned kt = e >> 13, r2 = e & 8191;
  const unsigned kg = r2 >> 11, r3 = r2 & 2047, o = r3 >> 3, j = r3 & 7;
  const unsigned ck = kt * 32 + kg * 8 + j;
  const unsigned k = ck >> 8, c = ck & 255;
  const float v = w_dcn[((size_t)o * C1_ + c) * 9 + k];
  ((unsigned short*)(wsb + WA_OFF))[e] = (unsigned short)f2bfu(v);
}

// ---------------------------------------------------------------------------
// dcn_mfma: out[o,p] = sum_ck Wa[ck,o] * col[ck,p], fused BN+SiLU.
// Block: O=256 x P=64, 512 thr = 8 waves (wave tile 64o x 32p, 4x2 frags).
// K-loop: 72 steps of BK=32, double-buffered LDS, on-the-fly col producer.
// grid = B * 64 p-tiles = 256 blocks.
// ---------------------------------------------------------------------------
__global__ __launch_bounds__(512) void dcn_mfma(const float* __restrict__ x,
                                                const char* __restrict__ wsb,
                                                float* __restrict__ out) {
  __shared__ short Ald[2][8192];  // [buf][kg4][o256][j8]
  __shared__ short Bld[2][2048];  // [buf][kg4][p64][j8]

  const int bid = blockIdx.x;
  const int pt = bid & 63, b = bid >> 6;
  const int tid = threadIdx.x;
  const int lane = tid & 63, wid = tid >> 6;
  const int wo = wid >> 1, wp = wid & 1;
  const int p = tid & 63;   // producer column
  const int cr = tid >> 6;  // producer ck-subrange (4 ck each)

  const unsigned short* Wa = (const unsigned short*)(wsb + WA_OFF);
  const int4* midx =
      (const int4*)(wsb + MIDX_OFF) + (size_t)b * KK_ * HW_ + pt * 64 + p;
  const float4* mwgt =
      (const float4*)(wsb + MWGT_OFF) + (size_t)b * KK_ * HW_ + pt * 64 + p;
  const float* xb = x + (size_t)b * C1_ * HW_;

  f32x4 acc[4][2];
#pragma unroll
  for (int i = 0; i < 4; ++i)
#pragma unroll
    for (int j = 0; j < 2; ++j) acc[i][j] = (f32x4){0.f, 0.f, 0.f, 0.f};

  int4 mi;
  float4 mw;

  auto stageA = [&](int kt, int buf) {
    const char* src = (const char*)(Wa + (size_t)kt * 8192);
#pragma unroll
    for (int r = 0; r < 2; ++r) {
      const int chunk = r * 512 + tid;
      gload_lds16(src + chunk * 16, (char*)&Ald[buf][0] + chunk * 16);
    }
  };

  auto produce = [&](int kt, int2& pk) {
    const int k = kt >> 3, c0 = (kt & 7) * 32;
    if ((kt & 7) == 0) {
      mi = midx[(size_t)k * HW_];
      mw = mwgt[(size_t)k * HW_];
    }
    const float* pl = xb + (size_t)(c0 + cr * 4) * HW_;
    unsigned bf[4];
#pragma unroll
    for (int i = 0; i < 4; ++i) {
      float v = mw.x * pl[mi.x] + mw.y * pl[mi.y] + mw.z * pl[mi.z] +
                mw.w * pl[mi.w];
      bf[i] = f2bfu(v);
      pl += HW_;
    }
    pk.x = bf[0] | (bf[1] << 16);
    pk.y = bf[2] | (bf[3] << 16);
  };

  const int bslot = (cr >> 1) * 512 + p * 8 + (cr & 1) * 4;

  auto compute = [&](int buf) {
    const int kg = lane >> 4, rr = lane & 15;
    bf16x8 af[4], bfr[2];
#pragma unroll
    for (int fm = 0; fm < 4; ++fm)
      af[fm] = *(const bf16x8*)&Ald[buf][kg * 2048 + (wo * 64 + fm * 16 + rr) * 8];
#pragma unroll
    for (int fn = 0; fn < 2; ++fn)
      bfr[fn] = *(const bf16x8*)&Bld[buf][kg * 512 + (wp * 32 + fn * 16 + rr) * 8];
#pragma unroll
    for (int fm = 0; fm < 4; ++fm)
#pragma unroll
      for (int fn = 0; fn < 2; ++fn)
        acc[fm][fn] = __builtin_amdgcn_mfma_f32_16x16x32_bf16(
            af[fm], bfr[fn], acc[fm][fn], 0, 0, 0);
  };

  // prologue: stage kt=0
  {
    int2 pk;
    stageA(0, 0);
    produce(0, pk);
    *(int2*)&Bld[0][bslot] = pk;
  }
  __syncthreads();

  auto iter = [&](int kt, int buf) {
    const int nxt = buf ^ 1;
    int2 pk;
    const bool pre = (kt < 71);
    if (pre) {
      stageA(kt + 1, nxt);
      produce(kt + 1, pk);
    }
    compute(buf);
    if (pre) *(int2*)&Bld[nxt][bslot] = pk;
    __syncthreads();
  };

  for (int kt = 0; kt < 72; kt += 2) {
    iter(kt, 0);
    iter(kt + 1, 1);
  }

  // epilogue: BN + SiLU + store
  const float* bninv = (const float*)(wsb + BN_OFF);
  const float* bnbb = bninv + 256;
  const int rr = lane & 15, rh = lane >> 4;
#pragma unroll
  for (int fm = 0; fm < 4; ++fm) {
#pragma unroll
    for (int r = 0; r < 4; ++r) {
      const int o = wo * 64 + fm * 16 + rh * 4 + r;
      const float inv = bninv[o], bb = bnbb[o];
#pragma unroll
      for (int fn = 0; fn < 2; ++fn) {
        float t = acc[fm][fn][r] * inv + bb;
        float s = t / (1.f + expf(-t));
        out[(size_t)(b * C2_ + o) * HW_ + pt * 64 + wp * 32 + fn * 16 + rr] = s;
      }
    }
  }
}

// ---------------------------------------------------------------------------
extern "C" void kernel_launch(void* const* d_in, const int* in_sizes, int n_in,
                              void* d_out, int out_size, void* d_ws,
                              size_t ws_size, hipStream_t stream) {
  const float* x = (const float*)d_in[0];
  const float* w_om = (const float*)d_in[1];
  const float* b_om = (const float*)d_in[2];
  const float* w_dcn = (const float*)d_in[3];
  const float* bn_gamma = (const float*)d_in[4];
  const float* bn_beta = (const float*)d_in[5];
  const float* bn_mean = (const float*)d_in[6];
  const float* bn_var = (const float*)d_in[7];
  float* out = (float*)d_out;
  char* wsb = (char*)d_ws;

  om_part<<<B_ * H_ * 4, 256, 0, stream>>>(x, w_om, wsb);
  om_final<<<64, 256, 0, stream>>>(b_om, bn_gamma, bn_beta, bn_mean, bn_var,
                                   wsb);
  wt_perm<<<2304, 256, 0, stream>>>(w_dcn, wsb);
  dcn_mfma<<<B_ * 64, 512, 0, stream>>>(x, wsb, out);
}

// Round 3
// 201.472 us; speedup vs baseline: 3.3606x; 1.6580x over previous
//
#include <hip/hip_runtime.h>
#include <math.h>

#define B_  4
#define C1_ 256
#define C2_ 256
#define H_  64
#define W_  64
#define HW_ 4096
#define KK_ 9

// ws byte offsets
#define WA_OFF    0u            // bf16 Wa[72][4][256][8]          (1,179,648 B)
#define MIDX_OFF  1179648u      // int4  midx[B][9][4096]          (2,359,296 B)
#define MWGT_OFF  3538944u      // float4 mwgt[B][9][4096]         (2,359,296 B)
#define WOM_OFF   5898240u      // bf16 Wom[72][4][32][8]          (147,456 B)
#define OM_OFF    6045696u      // float om[27][B*HW]              (1,769,472 B)
#define BN_OFF    7815168u      // float inv[256]; bb[256]         (2,048 B)

typedef short bf16x8 __attribute__((ext_vector_type(8)));
typedef float f32x4 __attribute__((ext_vector_type(4)));

__device__ __forceinline__ unsigned f2bfu(float f) {
  unsigned u = __builtin_bit_cast(unsigned, f);
  return (u + 0x7FFFu + ((u >> 16) & 1u)) >> 16;
}

__device__ __forceinline__ void gload_lds16(const void* g, void* l) {
  __builtin_amdgcn_global_load_lds(
      (const __attribute__((address_space(1))) unsigned*)g,
      (__attribute__((address_space(3))) unsigned*)l, 16, 0, 0);
}

// ---------------------------------------------------------------------------
// wom_perm: w_om [27][C1][9] -> Wom bf16 [72 kt][4 kg][32 o][8 j], ck=k*256+c,
// o padded 27->32 with zeros.
// ---------------------------------------------------------------------------
__global__ __launch_bounds__(256) void wom_perm(const float* __restrict__ w_om,
                                                char* __restrict__ wsb) {
  const unsigned e = blockIdx.x * 256 + threadIdx.x;  // < 73728
  const unsigned kt = e >> 10, kg = (e >> 8) & 3, o = (e >> 3) & 31,
                 j = e & 7;
  const unsigned ck = kt * 32 + kg * 8 + j;
  const unsigned k = ck >> 8, c = ck & 255;
  const float v = (o < 27) ? w_om[((size_t)o * C1_ + c) * 9 + k] : 0.f;
  ((unsigned short*)(wsb + WOM_OFF))[e] = (unsigned short)f2bfu(v);
}

// ---------------------------------------------------------------------------
// om_gemm: om[oc,p] = sum_ck Wom[ck,oc] * im2col(x)[ck,p]  (MFMA)
// Block: O=32 x P=64, 256 thr = 4 waves (2o x 2p), wave tile 16x32.
// K: 72 steps of BK=32, k-major (one shift per step), double-buffered LDS.
// grid = B*64 (block = one output row h of one batch).
// ---------------------------------------------------------------------------
__global__ __launch_bounds__(256) void om_gemm(const float* __restrict__ x,
                                               char* __restrict__ wsb) {
  __shared__ short Ald[2][1024];  // [buf][kg4][o32][j8]
  __shared__ short Bld[2][2048];  // [buf][kg4][p64][j8]

  const int bid = blockIdx.x;
  const int h = bid & 63, b = bid >> 6;
  const int tid = threadIdx.x;
  const int lane = tid & 63, wid = tid >> 6;
  const int wo = wid >> 1, wp = wid & 1;
  const int w = tid & 63;   // producer column (also == wave id grouping)
  const int cr = tid >> 6;  // producer ck-group (8 c each)

  const unsigned short* Wom = (const unsigned short*)(wsb + WOM_OFF);
  const float* xb = x + (size_t)b * C1_ * HW_;

  f32x4 acc[2];
#pragma unroll
  for (int j = 0; j < 2; ++j) acc[j] = (f32x4){0.f, 0.f, 0.f, 0.f};

  auto stageA = [&](int kt, int buf) {
    if (tid < 128)
      gload_lds16((const char*)(Wom + (size_t)kt * 1024) + tid * 16,
                  (char*)&Ald[buf][0] + tid * 16);
  };

  auto produce = [&](int kt, int4& pk) {
    const int k = kt >> 3;
    const int c0 = (kt & 7) * 32 + cr * 8;
    const int hh = h - 1 + k / 3, ww = w - 1 + k % 3;
    const bool v = ((unsigned)hh < (unsigned)H_) && ((unsigned)ww < (unsigned)W_);
    const float* pl = xb + (size_t)c0 * HW_ + (v ? hh * W_ + ww : 0);
    unsigned bf[8];
#pragma unroll
    for (int i = 0; i < 8; ++i) {
      float t = v ? pl[(size_t)i * HW_] : 0.f;
      bf[i] = f2bfu(t);
    }
    pk.x = bf[0] | (bf[1] << 16);
    pk.y = bf[2] | (bf[3] << 16);
    pk.z = bf[4] | (bf[5] << 16);
    pk.w = bf[6] | (bf[7] << 16);
  };

  const int bslot = cr * 512 + w * 8;

  auto compute = [&](int buf) {
    const int kg = lane >> 4, rr = lane & 15;
    bf16x8 af = *(const bf16x8*)&Ald[buf][kg * 256 + (wo * 16 + rr) * 8];
#pragma unroll
    for (int fn = 0; fn < 2; ++fn) {
      bf16x8 bfr =
          *(const bf16x8*)&Bld[buf][kg * 512 + (wp * 32 + fn * 16 + rr) * 8];
      acc[fn] = __builtin_amdgcn_mfma_f32_16x16x32_bf16(af, bfr, acc[fn], 0, 0, 0);
    }
  };

  {
    int4 pk;
    stageA(0, 0);
    produce(0, pk);
    *(int4*)&Bld[0][bslot] = pk;
  }
  __syncthreads();

  auto iter = [&](int kt, int buf) {
    const int nxt = buf ^ 1;
    int4 pk;
    const bool pre = (kt < 71);
    if (pre) {
      stageA(kt + 1, nxt);
      produce(kt + 1, pk);
    }
    compute(buf);
    if (pre) *(int4*)&Bld[nxt][bslot] = pk;
    __syncthreads();
  };

  for (int kt = 0; kt < 72; kt += 2) {
    iter(kt, 0);
    iter(kt + 1, 1);
  }

  // epilogue: store om rows (oc < 27)
  float* om = (float*)(wsb + OM_OFF);
  const int rr = lane & 15, rh = lane >> 4;
#pragma unroll
  for (int r = 0; r < 4; ++r) {
    const int oc = wo * 16 + rh * 4 + r;
    if (oc < 27) {
#pragma unroll
      for (int fn = 0; fn < 2; ++fn) {
        const int p = wp * 32 + fn * 16 + rr;
        om[(size_t)oc * (B_ * HW_) + b * HW_ + h * W_ + p] = acc[fn][r];
      }
    }
  }
}

// ---------------------------------------------------------------------------
// om_final: om + bias -> clamp/sigmoid -> bilinear meta (idx + premult wgts).
// Also BN prep (block 0). grid = 64 x 256 (one thread per (b,p)).
// ---------------------------------------------------------------------------
__global__ __launch_bounds__(256) void om_final(
    const float* __restrict__ b_om, const float* __restrict__ bn_gamma,
    const float* __restrict__ bn_beta, const float* __restrict__ bn_mean,
    const float* __restrict__ bn_var, char* __restrict__ wsb) {
  if (blockIdx.x == 0) {
    const int o = threadIdx.x;
    float inv = bn_gamma[o] * rsqrtf(bn_var[o] + 1e-5f);
    ((float*)(wsb + BN_OFF))[o] = inv;
    ((float*)(wsb + BN_OFF))[256 + o] = bn_beta[o] - bn_mean[o] * inv;
  }
  const int t = blockIdx.x * 256 + threadIdx.x;
  const int b = t >> 12, p = t & 4095;
  const int h = p >> 6, w = p & 63;

  const float* om = (const float*)(wsb + OM_OFF);
  float acc[27];
#pragma unroll
  for (int oc = 0; oc < 27; ++oc)
    acc[oc] = b_om[oc] + om[(size_t)oc * (B_ * HW_) + t];

  int4* midx = (int4*)(wsb + MIDX_OFF);
  float4* mwgt = (float4*)(wsb + MWGT_OFF);
#pragma unroll
  for (int k = 0; k < 9; ++k) {
    float dy = fminf(fmaxf(acc[2 * k], -6.f), 6.f);
    float dx = fminf(fmaxf(acc[2 * k + 1], -6.f), 6.f);
    float m = 1.f / (1.f + expf(-acc[18 + k]));
    float py = (float)(h - 1 + k / 3) + dy;
    float px = (float)(w - 1 + k % 3) + dx;
    float y0f = floorf(py), x0f = floorf(px);
    float ly = py - y0f, lx = px - x0f;
    int y0 = (int)y0f, x0 = (int)x0f;
    int y1 = y0 + 1, x1 = x0 + 1;
    const bool vy0 = ((unsigned)y0 < (unsigned)H_);
    const bool vy1 = ((unsigned)y1 < (unsigned)H_);
    const bool vx0 = ((unsigned)x0 < (unsigned)W_);
    const bool vx1 = ((unsigned)x1 < (unsigned)W_);
    int y0c = min(max(y0, 0), H_ - 1), y1c = min(max(y1, 0), H_ - 1);
    int x0c = min(max(x0, 0), W_ - 1), x1c = min(max(x1, 0), W_ - 1);
    const size_t e = ((size_t)b * KK_ + k) * HW_ + p;
    midx[e] = make_int4(y0c * W_ + x0c, y0c * W_ + x1c, y1c * W_ + x0c,
                        y1c * W_ + x1c);
    mwgt[e] = make_float4((1.f - ly) * (1.f - lx) * ((vy0 && vx0) ? m : 0.f),
                          (1.f - ly) * lx * ((vy0 && vx1) ? m : 0.f),
                          ly * (1.f - lx) * ((vy1 && vx0) ? m : 0.f),
                          ly * lx * ((vy1 && vx1) ? m : 0.f));
  }
}

// ---------------------------------------------------------------------------
// wt_perm: w_dcn [C2][C1][9] -> Wa bf16 [72 kt][4 kg][256 o][8 j], ck=k*256+c.
// ---------------------------------------------------------------------------
__global__ __launch_bounds__(256) void wt_perm(const float* __restrict__ w_dcn,
                                               char* __restrict__ wsb) {
  const unsigned e = blockIdx.x * 256 + threadIdx.x;  // < 589824
  const unsigned kt = e >> 13, r2 = e & 8191;
  const unsigned kg = r2 >> 11, r3 = r2 & 2047, o = r3 >> 3, j = r3 & 7;
  const unsigned ck = kt * 32 + kg * 8 + j;
  const unsigned k = ck >> 8, c = ck & 255;
  const float v = w_dcn[((size_t)o * C1_ + c) * 9 + k];
  ((unsigned short*)(wsb + WA_OFF))[e] = (unsigned short)f2bfu(v);
}

// ---------------------------------------------------------------------------
// dcn_mfma: out[o,p] = sum_ck Wa[ck,o] * col[ck,p], fused BN+SiLU.
// Block: O=256 x P=64, 512 thr = 8 waves (wave tile 64o x 32p, 4x2 frags).
// K-loop: 72 steps of BK=32, double-buffered LDS, on-the-fly col producer.
// grid = B * 64 p-tiles = 256 blocks.
// ---------------------------------------------------------------------------
__global__ __launch_bounds__(512) void dcn_mfma(const float* __restrict__ x,
                                                const char* __restrict__ wsb,
                                                float* __restrict__ out) {
  __shared__ short Ald[2][8192];  // [buf][kg4][o256][j8]
  __shared__ short Bld[2][2048];  // [buf][kg4][p64][j8]

  const int bid = blockIdx.x;
  const int pt = bid & 63, b = bid >> 6;
  const int tid = threadIdx.x;
  const int lane = tid & 63, wid = tid >> 6;
  const int wo = wid >> 1, wp = wid & 1;
  const int p = tid & 63;   // producer column
  const int cr = tid >> 6;  // producer ck-subrange (4 ck each)

  const unsigned short* Wa = (const unsigned short*)(wsb + WA_OFF);
  const int4* midx =
      (const int4*)(wsb + MIDX_OFF) + (size_t)b * KK_ * HW_ + pt * 64 + p;
  const float4* mwgt =
      (const float4*)(wsb + MWGT_OFF) + (size_t)b * KK_ * HW_ + pt * 64 + p;
  const float* xb = x + (size_t)b * C1_ * HW_;

  f32x4 acc[4][2];
#pragma unroll
  for (int i = 0; i < 4; ++i)
#pragma unroll
    for (int j = 0; j < 2; ++j) acc[i][j] = (f32x4){0.f, 0.f, 0.f, 0.f};

  int4 mi;
  float4 mw;

  auto stageA = [&](int kt, int buf) {
    const char* src = (const char*)(Wa + (size_t)kt * 8192);
#pragma unroll
    for (int r = 0; r < 2; ++r) {
      const int chunk = r * 512 + tid;
      gload_lds16(src + chunk * 16, (char*)&Ald[buf][0] + chunk * 16);
    }
  };

  auto produce = [&](int kt, int2& pk) {
    const int k = kt >> 3, c0 = (kt & 7) * 32;
    if ((kt & 7) == 0) {
      mi = midx[(size_t)k * HW_];
      mw = mwgt[(size_t)k * HW_];
    }
    const float* pl = xb + (size_t)(c0 + cr * 4) * HW_;
    unsigned bf[4];
#pragma unroll
    for (int i = 0; i < 4; ++i) {
      float v = mw.x * pl[mi.x] + mw.y * pl[mi.y] + mw.z * pl[mi.z] +
                mw.w * pl[mi.w];
      bf[i] = f2bfu(v);
      pl += HW_;
    }
    pk.x = bf[0] | (bf[1] << 16);
    pk.y = bf[2] | (bf[3] << 16);
  };

  const int bslot = (cr >> 1) * 512 + p * 8 + (cr & 1) * 4;

  auto compute = [&](int buf) {
    const int kg = lane >> 4, rr = lane & 15;
    bf16x8 af[4], bfr[2];
#pragma unroll
    for (int fm = 0; fm < 4; ++fm)
      af[fm] = *(const bf16x8*)&Ald[buf][kg * 2048 + (wo * 64 + fm * 16 + rr) * 8];
#pragma unroll
    for (int fn = 0; fn < 2; ++fn)
      bfr[fn] = *(const bf16x8*)&Bld[buf][kg * 512 + (wp * 32 + fn * 16 + rr) * 8];
#pragma unroll
    for (int fm = 0; fm < 4; ++fm)
#pragma unroll
      for (int fn = 0; fn < 2; ++fn)
        acc[fm][fn] = __builtin_amdgcn_mfma_f32_16x16x32_bf16(
            af[fm], bfr[fn], acc[fm][fn], 0, 0, 0);
  };

  {
    int2 pk;
    stageA(0, 0);
    produce(0, pk);
    *(int2*)&Bld[0][bslot] = pk;
  }
  __syncthreads();

  auto iter = [&](int kt, int buf) {
    const int nxt = buf ^ 1;
    int2 pk;
    const bool pre = (kt < 71);
    if (pre) {
      stageA(kt + 1, nxt);
      produce(kt + 1, pk);
    }
    compute(buf);
    if (pre) *(int2*)&Bld[nxt][bslot] = pk;
    __syncthreads();
  };

  for (int kt = 0; kt < 72; kt += 2) {
    iter(kt, 0);
    iter(kt + 1, 1);
  }

  // epilogue: BN + SiLU + store
  const float* bninv = (const float*)(wsb + BN_OFF);
  const float* bnbb = bninv + 256;
  const int rr = lane & 15, rh = lane >> 4;
#pragma unroll
  for (int fm = 0; fm < 4; ++fm) {
#pragma unroll
    for (int r = 0; r < 4; ++r) {
      const int o = wo * 64 + fm * 16 + rh * 4 + r;
      const float inv = bninv[o], bb = bnbb[o];
#pragma unroll
      for (int fn = 0; fn < 2; ++fn) {
        float t = acc[fm][fn][r] * inv + bb;
        float s = t / (1.f + expf(-t));
        out[(size_t)(b * C2_ + o) * HW_ + pt * 64 + wp * 32 + fn * 16 + rr] = s;
      }
    }
  }
}

// ---------------------------------------------------------------------------
extern "C" void kernel_launch(void* const* d_in, const int* in_sizes, int n_in,
                              void* d_out, int out_size, void* d_ws,
                              size_t ws_size, hipStream_t stream) {
  const float* x = (const float*)d_in[0];
  const float* w_om = (const float*)d_in[1];
  const float* b_om = (const float*)d_in[2];
  const float* w_dcn = (const float*)d_in[3];
  const float* bn_gamma = (const float*)d_in[4];
  const float* bn_beta = (const float*)d_in[5];
  const float* bn_mean = (const float*)d_in[6];
  const float* bn_var = (const float*)d_in[7];
  float* out = (float*)d_out;
  char* wsb = (char*)d_ws;

  wom_perm<<<288, 256, 0, stream>>>(w_om, wsb);
  wt_perm<<<2304, 256, 0, stream>>>(w_dcn, wsb);
  om_gemm<<<B_ * 64, 256, 0, stream>>>(x, wsb);
  om_final<<<64, 256, 0, stream>>>(b_om, bn_gamma, bn_beta, bn_mean, bn_var,
                                   wsb);
  dcn_mfma<<<B_ * 64, 512, 0, stream>>>(x, wsb, out);
}